// Round 1
// 243.833 us; speedup vs baseline: 1.0281x; 1.0281x over previous
//
#include <hip/hip_runtime.h>
#include <hip/hip_bf16.h>
#include <stdint.h>

// ---- types ----
typedef float   floatx4  __attribute__((ext_vector_type(4)));
typedef int     intx4    __attribute__((ext_vector_type(4)));
typedef int     intx8    __attribute__((ext_vector_type(8)));
typedef _Float16 halfx8  __attribute__((ext_vector_type(8)));
typedef _Float16 halfx4  __attribute__((ext_vector_type(4)));
typedef _Float16 half2v  __attribute__((ext_vector_type(2)));
typedef short   short2v  __attribute__((ext_vector_type(2)));
typedef unsigned short ushort8 __attribute__((ext_vector_type(8)));

#define NROW 8192
#define NDIM 2048        // elements = bytes (fp8)
#define BM 128
#define BKB 128          // bytes per row per K-stage = 128 fp8 = 8 x 16B chunks
#define NSTRIP 64                       // NROW/BM
#define NOFF (NSTRIP*(NSTRIP-1)/2)      // 2016 off-diagonal tiles (dispatched first)
#define NTILE (NSTRIP*(NSTRIP+1)/2)     // 2080 total tiles
#define DT_LD 136        // Dt row stride in halves (272 B; rows 16B-aligned)
#define KL_SYM 64        // one 5-list per row per other-strip
#define MERGE_BLOCKS 128 // k_merge_sym grid

// insert v into descending-sorted a[5] (keeps 5 largest)  [f32 scalar]
__device__ __forceinline__ void ins_desc(float (&a)[5], float v) {
#pragma unroll
    for (int k = 0; k < 5; ++k) { float hi = fmaxf(a[k], v); float lo = fminf(a[k], v); a[k] = hi; v = lo; }
}
// insert v into ascending-sorted a[5] (keeps 5 smallest)  [f32 scalar]
__device__ __forceinline__ void ins_asc(float (&a)[5], float v) {
#pragma unroll
    for (int k = 0; k < 5; ++k) { float lo = fminf(a[k], v); float hi = fmaxf(a[k], v); a[k] = lo; v = hi; }
}

// ---- packed-f16 helpers (R12): v_pk_* process 2 columns per instruction ----
__device__ __forceinline__ int   h2bits(half2v v) { return __builtin_bit_cast(int, v); }
__device__ __forceinline__ half2v bits2h(int v)   { return __builtin_bit_cast(half2v, v); }
// (m & a) | (~m & b) -> v_bfi_b32
__device__ __forceinline__ int bfi(int m, int a, int b) { return (m & a) | (~m & b); }
// per-16-bit-half: 0xFFFF if half != 0 (general; halves may exceed 0x7FFF)
__device__ __forceinline__ int nzmask16(int v) {
    short2v s = __builtin_bit_cast(short2v, v);
    short2v n = (short2v)(0) - s;                 // v_pk_sub_i16
    int o = v | __builtin_bit_cast(int, n);       // sign set iff half != 0
    short2v m = __builtin_bit_cast(short2v, o) >> 15;  // v_pk_ashrrev_i16
    return __builtin_bit_cast(int, m);
}
// per-16-bit-half: 0xFFFF if half != 0; requires halves < 0x8000 (true for cam nibble)
__device__ __forceinline__ int nzmask16_small(int v) {
    short2v s = __builtin_bit_cast(short2v, v);
    short2v n = (short2v)(0) - s;                 // v_pk_sub_i16 (sign set iff 0<half<0x8000)
    short2v m = n >> 15;                          // v_pk_ashrrev_i16
    return __builtin_bit_cast(int, m);
}
// packed insertion: two independent desc-sorted top-5 lists (lo/hi half)
__device__ __forceinline__ void ins_desc2(half2v (&a)[5], half2v v) {
#pragma unroll
    for (int k = 0; k < 5; ++k) {
        half2v hi = __builtin_elementwise_max(a[k], v);
        half2v lo = __builtin_elementwise_min(a[k], v);
        a[k] = hi; v = lo;
    }
}
__device__ __forceinline__ void ins_asc2(half2v (&a)[5], half2v v) {
#pragma unroll
    for (int k = 0; k < 5; ++k) {
        half2v lo = __builtin_elementwise_min(a[k], v);
        half2v hi = __builtin_elementwise_max(a[k], v);
        a[k] = lo; v = hi;
    }
}

__device__ __forceinline__ void load_lds16(const void* g, void* l) {
    // async global->LDS, 16B/lane, dest = wave-uniform base + lane*16
    __builtin_amdgcn_global_load_lds((__attribute__((address_space(1))) void*)(void*)g,
                                     (__attribute__((address_space(3))) void*)l,
                                     16, 0, 0);
}

// ---- kernel 1: L2 normalize rows, write fp8-e4m3 matrix + sq ----
// fp8 verified numerically in R8/R9 (absmax 0.0078 == bf16 path).
__global__ __launch_bounds__(256) void k_normalize(const float* __restrict__ feats,
                                                   unsigned char* __restrict__ xb,
                                                   float* __restrict__ sq) {
    const int row = blockIdx.x;
    const int t = threadIdx.x;
    const float* f = feats + (size_t)row * NDIM + t * 8;
    float4 v0 = *(const float4*)(f);
    float4 v1 = *(const float4*)(f + 4);
    float ss = v0.x*v0.x + v0.y*v0.y + v0.z*v0.z + v0.w*v0.w
             + v1.x*v1.x + v1.y*v1.y + v1.z*v1.z + v1.w*v1.w;
#pragma unroll
    for (int o = 32; o > 0; o >>= 1) ss += __shfl_down(ss, o);
    __shared__ float red[4];
    __shared__ float s_inv;
    if ((t & 63) == 0) red[t >> 6] = ss;
    __syncthreads();
    if (t == 0) {
        float tot = red[0] + red[1] + red[2] + red[3];
        float m = fmaxf(sqrtf(tot), 1e-12f);
        float inv = 1.0f / m;
        sq[row] = tot * inv * inv;
        s_inv = inv;
    }
    __syncthreads();
    float inv = s_inv;
    // pack 8 normalized floats -> 8 fp8 e4m3 (HW cvt)
    int w0 = __builtin_amdgcn_cvt_pk_fp8_f32(v0.x * inv, v0.y * inv, 0, false);
    w0     = __builtin_amdgcn_cvt_pk_fp8_f32(v0.z * inv, v0.w * inv, w0, true);
    int w1 = __builtin_amdgcn_cvt_pk_fp8_f32(v1.x * inv, v1.y * inv, 0, false);
    w1     = __builtin_amdgcn_cvt_pk_fp8_f32(v1.z * inv, v1.w * inv, w1, true);
    int2 pk; pk.x = w0; pk.y = w1;
    *(int2*)(xb + (size_t)row * NDIM + t * 8) = pk;
}

// ---- scan helper (R12: packed-f16, 2 cols/instruction) ----
// Chunk swizzle changed XOR -> additive rotate:  phys = (logical + 2*(row&7)) & 15.
// Bank base of a b128 scan read = 4*((3*(row&7) + chunk) mod 8); 3 is invertible
// mod 8 so the 8 row-classes map to 8 disjoint 4-bank windows -> 8-phase floor
// (XOR swizzle gave s + (c8^s), NOT a permutation -> 16 phases, the 1.55e7
// SQ_LDS_BANK_CONFLICT).
// Classification in packed i16 domain; selection values compared/stored in f16
// (the emitted lists were ALREADY f16, so only the boost product rounding moves:
// half(1/1.44)=0x398E, 1.6e-4 relative -> ~1e-4 on d_an, inside tolerance).
__device__ __forceinline__ void scan_half_row(const _Float16* Dt_,
        const unsigned short* labcam_cols,
        int srow, int shalf, int pli, float (&pos5)[5], float (&neg5)[5]) {
    const int jb = shalf * 64;
    const int s2 = 2 * (srow & 7);
    const int pli2 = pli * 0x00010001;
    const int ONE2  = 0x3C003C00;   // half2(1.0, 1.0)
    const int BOOST2= 0x398E398E;   // half2(1/1.44) = 0.694336
    const int PINF2 = 0x7C007C00;
    const int NINF2 = 0xFC00FC00;
    half2v p5[5], n5[5];
#pragma unroll
    for (int k = 0; k < 5; ++k) { p5[k] = bits2h(NINF2); n5[k] = bits2h(PINF2); }
#pragma unroll
    for (int c8 = 0; c8 < 8; ++c8) {
        const int pc = ((shalf * 8 + c8) + s2) & 15;      // physical 16B chunk
        intx4 v  = *(const intx4*)(Dt_ + srow * DT_LD + pc * 8);
        intx4 lc = *(const intx4*)(labcam_cols + jb + c8 * 8);
#pragma unroll
        for (int e = 0; e < 4; ++e) {
            const int d2p = v[e];                 // 2 packed f16 d2 values
            const int x   = pli2 ^ lc[e];         // 2 packed (label<<4|cam) xors
            const int mdl = nzmask16(x & 0xFFF0FFF0);       // FFFF = diff label
            const int mdc = nzmask16_small(x & 0x000F000F); // FFFF = diff cam
            // negative: diff label; same-cam boost d2 * (1/1.44) (monotone in dist/1.2)
            const int mul = bfi(mdc, ONE2, BOOST2);
            half2v nv = bits2h(d2p) * bits2h(mul);          // v_pk_mul_f16
            nv = bits2h(bfi(mdl, h2bits(nv), PINF2));       // same-label -> +inf
            ins_asc2(n5, nv);                               // unconditional: P(any-lane insert)~1
            // positive: same label AND diff cam (i==j auto-excluded: same cam)
            const int pmask = mdc & ~mdl;
            half2v pv = bits2h(bfi(pmask, d2p, NINF2));
            half2v chk = __builtin_elementwise_max(pv, p5[4]);
            if (h2bits(chk) != h2bits(p5[4])) ins_desc2(p5, pv);  // ~40% taken
        }
    }
    // fold hi-halves into lo halves: rotate 16 and insert (top5 ⊆ union of half-top5s)
    half2v tp[5], tn[5];
#pragma unroll
    for (int k = 0; k < 5; ++k) {
        tp[k] = bits2h((int)__builtin_amdgcn_alignbit((unsigned)h2bits(p5[k]), (unsigned)h2bits(p5[k]), 16));
        tn[k] = bits2h((int)__builtin_amdgcn_alignbit((unsigned)h2bits(n5[k]), (unsigned)h2bits(n5[k]), 16));
    }
#pragma unroll
    for (int k = 0; k < 5; ++k) { ins_desc2(p5, tp[k]); ins_asc2(n5, tn[k]); }
#pragma unroll
    for (int k = 0; k < 5; ++k) { pos5[k] = (float)p5[k][0]; neg5[k] = (float)n5[k][0]; }
}

// merge the two half-row lists (adjacent lanes; snapshot-then-insert) and emit fp16
__device__ __forceinline__ void emit_lists(float (&pos5)[5], float (&neg5)[5], int shalf,
        _Float16* posp, _Float16* negp, size_t gi, int slot) {
    float tp[5], tn[5];
#pragma unroll
    for (int k = 0; k < 5; ++k) { tp[k] = __shfl_xor(pos5[k], 1); tn[k] = __shfl_xor(neg5[k], 1); }
#pragma unroll
    for (int k = 0; k < 5; ++k) {
        if (tp[k] > pos5[4]) ins_desc(pos5, tp[k]);
        if (tn[k] < neg5[4]) ins_asc(neg5, tn[k]);
    }
    if (shalf == 0) {
        _Float16* pp = posp + (gi * KL_SYM + slot) * 5;
        _Float16* np = negp + (gi * KL_SYM + slot) * 5;
#pragma unroll
        for (int k = 0; k < 5; ++k) { pp[k] = (_Float16)pos5[k]; np[k] = (_Float16)neg5[k]; }
    }
}

// ---- kernel 2 (sym): R9 structure + R12 packed scan / additive Dt swizzle.
// One block per triangle tile (a,b), b<=a; diagonals last.  MX-fp8 K-loop,
// 4 waves x 64x64 wave-tile (4x4 MFMA accs; read:MFMA = 1.0), (256,3) cap
// (R10: acc counts against unified-file cap; (256,4) spills).
__global__ __launch_bounds__(256, 3) void k_gemm_sym(
        const unsigned char* __restrict__ xb, const float* __restrict__ sq,
        const int* __restrict__ labels, const int* __restrict__ camids,
        _Float16* __restrict__ posp, _Float16* __restrict__ negp) {
    __shared__ __align__(16) char smem[BM * DT_LD * 2 + 4 * BM * 4];
    char* As = smem;                          // [0, 16384)
    char* Bs = smem + BM * BKB;               // [16384, 32768)
    _Float16* Dt = (_Float16*)smem;           // [0, 34816) aliases As/Bs
    float* sqr_s = (float*)(smem + BM * DT_LD * 2);
    float* sqc_s = sqr_s + BM;
    unsigned short* labcam_a = (unsigned short*)(sqc_s + BM);
    unsigned short* labcam_b = labcam_a + BM;

    const int tid = threadIdx.x;
    const int w = tid >> 6, lane = tid & 63;
    const int wm = w >> 1, wn = w & 1;

    // tile decode: off-diagonal pairs (b<a) first, diagonals last (cheap tail)
    int a, b;
    {
        int bx = blockIdx.x;
        if (bx < NOFF) {
            a = (int)((1.0f + sqrtf(8.0f * (float)bx + 1.0f)) * 0.5f);
            while (a * (a - 1) / 2 > bx) --a;
            while (a * (a + 1) / 2 <= bx) ++a;
            b = bx - a * (a - 1) / 2;
        } else {
            a = b = bx - NOFF;
        }
    }
    const int r0 = a * BM, c0 = b * BM;

    if (tid < BM) {
        int gi = r0 + tid;
        sqr_s[tid] = sq[gi];
        labcam_a[tid] = (unsigned short)((labels[gi] << 4) | camids[gi]);
    } else {
        int t2 = tid - BM;
        int gj = c0 + t2;
        sqc_s[t2] = sq[gj];
        labcam_b[t2] = (unsigned short)((labels[gj] << 4) | camids[gj]);
    }
    __syncthreads();

    const int srow = tid >> 1;       // scan: 2 threads per row
    const int shalf = tid & 1;

    const int lr = lane >> 3;                  // staging: row within 8-row chunk
    const int lc = ((lane & 7) ^ lr) * 16;     // staging: swizzled source chunk, bytes
    const int m16 = lane & 15;
    const int quad = lane >> 4;
    const int s7 = m16 & 7;                    // frag-read swizzle key (= row&7)
    const int pc0 = ((2 * quad) ^ s7) * 16;    // physical byte offset of logical chunk 2q
    const int pc1 = ((2 * quad + 1) ^ s7) * 16;

    floatx4 acc[4][4];
#pragma unroll
    for (int mi = 0; mi < 4; ++mi)
#pragma unroll
        for (int ni = 0; ni < 4; ++ni) {
            floatx4 z = {0.f, 0.f, 0.f, 0.f};
            acc[mi][ni] = z;
        }

    for (int kk = 0; kk < NDIM; kk += BKB) {   // 16 stages
        __syncthreads();             // previous iter's LDS consumers done
#pragma unroll
        for (int q = 0; q < 4; ++q) {
            const int ra = w * 32 + q * 8;    // wave-uniform 8-row chunk base
            load_lds16(xb + (size_t)(r0 + ra + lr) * NDIM + kk + lc, As + ra * BKB);
            load_lds16(xb + (size_t)(c0 + ra + lr) * NDIM + kk + lc, Bs + ra * BKB);
        }
        __syncthreads();             // drains vmcnt(0): data in LDS
        intx8 bfr[4];
#pragma unroll
        for (int ni = 0; ni < 4; ++ni) {
            const char* bp = Bs + (wn * 64 + ni * 16 + m16) * BKB;
            intx4 lo = *(const intx4*)(bp + pc0);
            intx4 hi = *(const intx4*)(bp + pc1);
            bfr[ni] = __builtin_shufflevector(lo, hi, 0, 1, 2, 3, 4, 5, 6, 7);
        }
#pragma unroll
        for (int mi = 0; mi < 4; ++mi) {
            const char* ap = As + (wm * 64 + mi * 16 + m16) * BKB;
            intx4 lo = *(const intx4*)(ap + pc0);
            intx4 hi = *(const intx4*)(ap + pc1);
            intx8 af = __builtin_shufflevector(lo, hi, 0, 1, 2, 3, 4, 5, 6, 7);
#pragma unroll
            for (int ni = 0; ni < 4; ++ni)
                acc[mi][ni] = __builtin_amdgcn_mfma_scale_f32_16x16x128_f8f6f4(
                    af, bfr[ni], acc[mi][ni], 0, 0, 0, 127, 0, 127);
        }
    }
    __syncthreads();                 // all ds_reads of As/Bs done before Dt overwrite

    // ---- pass 1: d2 row-major (additive chunk rotate); scan rows of strip a ----
    // 16x16 C layout: col = lane&15, row = quad*4 + reg
#pragma unroll
    for (int mi = 0; mi < 4; ++mi) {
        const int il = wm * 64 + mi * 16 + quad * 4;
#pragma unroll
        for (int ni = 0; ni < 4; ++ni) {
            const int jl = wn * 64 + ni * 16 + m16;
            const float sj = sqc_s[jl];
#pragma unroll
            for (int r = 0; r < 4; ++r) {
                float d2 = fmaxf(sqr_s[il + r] + sj - 2.0f * acc[mi][ni][r], 1e-12f);
                const int pch = (((jl >> 3) + 2 * ((il + r) & 7)) & 15);
                Dt[(il + r) * DT_LD + (pch << 3) + (jl & 7)] = (_Float16)d2;
            }
        }
    }
    __syncthreads();

    float pos5[5], neg5[5];
    scan_half_row(Dt, labcam_b, srow, shalf, (int)labcam_a[srow], pos5, neg5);
    emit_lists(pos5, neg5, shalf, posp, negp, (size_t)(r0 + srow), b);

    if (a != b) {
        __syncthreads();             // pass-1 scan reads done before Dt overwrite
        // ---- pass 2: d2 transposed (b64 packed, additive rotate); scan rows of strip b ----
#pragma unroll
        for (int ni = 0; ni < 4; ++ni) {
            const int jl = wn * 64 + ni * 16 + m16;
            const float sj = sqc_s[jl];
            const int cw2 = 2 * (jl & 7);
#pragma unroll
            for (int mi = 0; mi < 4; ++mi) {
                const int il = wm * 64 + mi * 16 + quad * 4;
                halfx4 h;
#pragma unroll
                for (int r = 0; r < 4; ++r)
                    h[r] = (_Float16)fmaxf(sqr_s[il + r] + sj - 2.0f * acc[mi][ni][r], 1e-12f);
                const int pch = (((il >> 3) + cw2) & 15);
                *(halfx4*)(Dt + jl * DT_LD + (pch << 3) + (il & 7)) = h;
            }
        }
        __syncthreads();
        scan_half_row(Dt, labcam_a, srow, shalf, (int)labcam_b[srow], pos5, neg5);
        emit_lists(pos5, neg5, shalf, posp, negp, (size_t)(c0 + srow), a);
    }
}

// ---- kernel 3: merge 64 fp16 d2-lists/row, 4 thr/row.  128 blocks x 256 thr ----
__global__ __launch_bounds__(256) void k_merge_sym(const _Float16* __restrict__ posp,
        const _Float16* __restrict__ negp, const int* __restrict__ epoch_p,
        float* __restrict__ out, float* __restrict__ wsum_p, float* __restrict__ wpsum_p) {
    const int t = threadIdx.x;
    const int rq = t & 3;                       // quarter of the row's 320 halves
    const int row = blockIdx.x * 64 + (t >> 2);
    const float NINF = -__builtin_inff(), PINF = __builtin_inff();
    float p5[5] = {NINF, NINF, NINF, NINF, NINF};
    float n5[5] = {PINF, PINF, PINF, PINF, PINF};
    const halfx8* pv8 = (const halfx8*)(posp + (size_t)row * (KL_SYM * 5) + rq * 80);
    const halfx8* nv8 = (const halfx8*)(negp + (size_t)row * (KL_SYM * 5) + rq * 80);
#pragma unroll
    for (int k = 0; k < 10; ++k) {
        halfx8 v = pv8[k];
#pragma unroll
        for (int e = 0; e < 8; ++e) { float f = (float)v[e]; if (f > p5[4]) ins_desc(p5, f); }
    }
#pragma unroll
    for (int k = 0; k < 10; ++k) {
        halfx8 v = nv8[k];
#pragma unroll
        for (int e = 0; e < 8; ++e) { float f = (float)v[e]; if (f < n5[4]) ins_asc(n5, f); }
    }
    // butterfly merge across the 4 lanes of this row (snapshot-then-insert)
#pragma unroll
    for (int o = 1; o <= 2; o <<= 1) {
        float tp[5], tn[5];
#pragma unroll
        for (int k = 0; k < 5; ++k) { tp[k] = __shfl_xor(p5[k], o); tn[k] = __shfl_xor(n5[k], o); }
#pragma unroll
        for (int k = 0; k < 5; ++k) {
            if (tp[k] > p5[4]) ins_desc(p5, tp[k]);
            if (tn[k] < n5[4]) ins_asc(n5, tn[k]);
        }
    }
    // d2 -> dist on the 5 survivors only
    float s = 0.f; int c = 0;
#pragma unroll
    for (int k = 0; k < 5; ++k) { bool fin = (p5[k] > NINF); s += fin ? sqrtf(p5[k]) : 0.f; c += fin ? 1 : 0; }
    float d_ap = (c > 0) ? s / (float)c : NINF;
    s = 0.f; c = 0;
#pragma unroll
    for (int k = 0; k < 5; ++k) { bool fin = (n5[k] < PINF); s += fin ? sqrtf(n5[k]) : 0.f; c += fin ? 1 : 0; }
    float d_an = (c > 0) ? s / (float)c : PINF;

    float w0 = 0.f, wp = 0.f;
    if (rq == 0) {
        out[1 + row] = d_ap;
        out[1 + NROW + row] = d_an;
        float diff = d_ap - d_an;
        w0 = 1.0f / (1.0f + expf(-2.0f * diff));         // sigmoid(ALPHA*(d_ap-d_an))
        float p;
        if (*epoch_p < 10) {
            p = fmaxf(diff, 0.0f) + log1pf(expf(-fabsf(diff)));  // stable softplus
        } else {
            p = fmaxf(diff + 0.3f, 0.0f);                // relu(d_ap - d_an + MARGIN)
        }
        wp = w0 * p;
    }
#pragma unroll
    for (int o = 32; o > 0; o >>= 1) { w0 += __shfl_down(w0, o); wp += __shfl_down(wp, o); }
    __shared__ float rw[4], rp[4];
    if ((t & 63) == 0) { rw[t >> 6] = w0; rp[t >> 6] = wp; }
    __syncthreads();
    if (t == 0) {
        wsum_p[blockIdx.x]  = rw[0] + rw[1] + rw[2] + rw[3];
        wpsum_p[blockIdx.x] = rp[0] + rp[1] + rp[2] + rp[3];
    }
}

// ---- kernel 4: finalize loss scalar (R12: parallel wave reduce, was serial loop) ----
__global__ void k_finalize(const float* __restrict__ wsum_p, const float* __restrict__ wpsum_p,
                           float* __restrict__ out) {
    const int t = threadIdx.x;   // 64 threads, MERGE_BLOCKS = 128
    float sw  = wsum_p[t]  + wsum_p[t + 64];
    float swp = wpsum_p[t] + wpsum_p[t + 64];
#pragma unroll
    for (int o = 32; o > 0; o >>= 1) { sw += __shfl_down(sw, o); swp += __shfl_down(swp, o); }
    if (t == 0) {
        float M = fmaxf(sw / (float)NROW, 1e-12f);
        out[0] = swp / ((float)NROW * M);
    }
}

extern "C" void kernel_launch(void* const* d_in, const int* in_sizes, int n_in,
                              void* d_out, int out_size, void* d_ws, size_t ws_size,
                              hipStream_t stream) {
    const float* feats  = (const float*)d_in[0];
    const int*   labels = (const int*)d_in[1];
    const int*   camids = (const int*)d_in[2];
    const int*   epoch  = (const int*)d_in[3];
    float* out = (float*)d_out;
    char* ws = (char*)d_ws;

    // workspace layout (~27.3 MB; ws proven >= 44 MB in R4-R11)
    unsigned char* xb = (unsigned char*)ws;                            // 16,777,216 B
    float* sq = (float*)(ws + 16777216);                               //     32,768 B
    const size_t HALF_LIST_BYTES = (size_t)NROW * KL_SYM * 5 * 2;      //  5,242,880 B
    _Float16* posp = (_Float16*)(ws + 16777216 + 32768);
    _Float16* negp = (_Float16*)(ws + 16777216 + 32768 + HALF_LIST_BYTES);
    float* wsum_p  = (float*)(ws + 16777216 + 32768 + 2 * HALF_LIST_BYTES);
    float* wpsum_p = wsum_p + MERGE_BLOCKS;

    k_normalize<<<NROW, 256, 0, stream>>>(feats, xb, sq);
    k_gemm_sym<<<NTILE, 256, 0, stream>>>(xb, sq, labels, camids, posp, negp);
    k_merge_sym<<<MERGE_BLOCKS, 256, 0, stream>>>(posp, negp, epoch, out, wsum_p, wpsum_p);
    k_finalize<<<1, 64, 0, stream>>>(wsum_p, wpsum_p, out);
}

// Round 2
// 242.774 us; speedup vs baseline: 1.0326x; 1.0044x over previous
//
#include <hip/hip_runtime.h>
#include <hip/hip_bf16.h>
#include <stdint.h>

// ---- types ----
typedef float   floatx4  __attribute__((ext_vector_type(4)));
typedef int     intx4    __attribute__((ext_vector_type(4)));
typedef int     intx8    __attribute__((ext_vector_type(8)));
typedef _Float16 halfx8  __attribute__((ext_vector_type(8)));
typedef _Float16 halfx4  __attribute__((ext_vector_type(4)));
typedef _Float16 half2v  __attribute__((ext_vector_type(2)));
typedef short   short2v  __attribute__((ext_vector_type(2)));
typedef unsigned short ushort8 __attribute__((ext_vector_type(8)));

#define NROW 8192
#define NDIM 2048        // elements = bytes (fp8)
#define BM 128
#define BKB 128          // bytes per row per K-stage = 128 fp8 = 8 x 16B chunks
#define NSTRIP 64                       // NROW/BM
#define NOFF (NSTRIP*(NSTRIP-1)/2)      // 2016 off-diagonal tiles (dispatched first)
#define NTILE (NSTRIP*(NSTRIP+1)/2)     // 2080 total tiles
#define DT_LD 136        // Dt row stride in halves (272 B; rows 16B-aligned)
#define KL_SYM 64        // one 5-list per row per other-strip
#define SLOT_P 8         // halves per list slot: 5 values + 3 sentinel pads (16B)
#define MERGE_BLOCKS 256 // k_merge_sym grid (R13: 128 -> 256, fill all CUs)

// insert v into descending-sorted a[5] (keeps 5 largest)  [f32 scalar]
__device__ __forceinline__ void ins_desc(float (&a)[5], float v) {
#pragma unroll
    for (int k = 0; k < 5; ++k) { float hi = fmaxf(a[k], v); float lo = fminf(a[k], v); a[k] = hi; v = lo; }
}
// insert v into ascending-sorted a[5] (keeps 5 smallest)  [f32 scalar]
__device__ __forceinline__ void ins_asc(float (&a)[5], float v) {
#pragma unroll
    for (int k = 0; k < 5; ++k) { float lo = fminf(a[k], v); float hi = fmaxf(a[k], v); a[k] = lo; v = hi; }
}

// ---- packed-f16 helpers (R12): v_pk_* process 2 columns per instruction ----
__device__ __forceinline__ int   h2bits(half2v v) { return __builtin_bit_cast(int, v); }
__device__ __forceinline__ half2v bits2h(int v)   { return __builtin_bit_cast(half2v, v); }
// (m & a) | (~m & b) -> v_bfi_b32
__device__ __forceinline__ int bfi(int m, int a, int b) { return (m & a) | (~m & b); }
// per-16-bit-half: 0xFFFF if half != 0 (general; halves may exceed 0x7FFF)
__device__ __forceinline__ int nzmask16(int v) {
    short2v s = __builtin_bit_cast(short2v, v);
    short2v n = (short2v)(0) - s;                 // v_pk_sub_i16
    int o = v | __builtin_bit_cast(int, n);       // sign set iff half != 0
    short2v m = __builtin_bit_cast(short2v, o) >> 15;  // v_pk_ashrrev_i16
    return __builtin_bit_cast(int, m);
}
// per-16-bit-half: 0xFFFF if half != 0; requires halves < 0x8000 (true for cam nibble)
__device__ __forceinline__ int nzmask16_small(int v) {
    short2v s = __builtin_bit_cast(short2v, v);
    short2v n = (short2v)(0) - s;                 // v_pk_sub_i16 (sign set iff 0<half<0x8000)
    short2v m = n >> 15;                          // v_pk_ashrrev_i16
    return __builtin_bit_cast(int, m);
}
// packed insertion: two independent desc-sorted top-5 lists (lo/hi half)
__device__ __forceinline__ void ins_desc2(half2v (&a)[5], half2v v) {
#pragma unroll
    for (int k = 0; k < 5; ++k) {
        half2v hi = __builtin_elementwise_max(a[k], v);
        half2v lo = __builtin_elementwise_min(a[k], v);
        a[k] = hi; v = lo;
    }
}
__device__ __forceinline__ void ins_asc2(half2v (&a)[5], half2v v) {
#pragma unroll
    for (int k = 0; k < 5; ++k) {
        half2v lo = __builtin_elementwise_min(a[k], v);
        half2v hi = __builtin_elementwise_max(a[k], v);
        a[k] = lo; v = hi;
    }
}

__device__ __forceinline__ void load_lds16(const void* g, void* l) {
    // async global->LDS, 16B/lane, dest = wave-uniform base + lane*16
    __builtin_amdgcn_global_load_lds((__attribute__((address_space(1))) void*)(void*)g,
                                     (__attribute__((address_space(3))) void*)l,
                                     16, 0, 0);
}

// ---- kernel 1: L2 normalize rows, write fp8-e4m3 matrix + sq ----
// R13: one wave per row (4 rows/block), no barriers, no LDS, stride-64
// interleaved accesses (each load/store instruction fully coalesced).
__global__ __launch_bounds__(256) void k_normalize(const float* __restrict__ feats,
                                                   unsigned char* __restrict__ xb,
                                                   float* __restrict__ sq) {
    const int lane = threadIdx.x & 63;
    const int row = (blockIdx.x << 2) + (threadIdx.x >> 6);
    const float* f = feats + (size_t)row * NDIM;
    float4 v[8];
    float ss = 0.f;
#pragma unroll
    for (int i = 0; i < 8; ++i) {
        v[i] = *(const float4*)(f + ((i << 6) + lane) * 4);
        ss += v[i].x * v[i].x + v[i].y * v[i].y + v[i].z * v[i].z + v[i].w * v[i].w;
    }
#pragma unroll
    for (int o = 32; o > 0; o >>= 1) ss += __shfl_xor(ss, o);
    float inv = 1.0f / fmaxf(sqrtf(ss), 1e-12f);
    if (lane == 0) sq[row] = ss * inv * inv;
    unsigned char* xo = xb + (size_t)row * NDIM;
#pragma unroll
    for (int i = 0; i < 8; ++i) {
        int w0 = __builtin_amdgcn_cvt_pk_fp8_f32(v[i].x * inv, v[i].y * inv, 0, false);
        w0     = __builtin_amdgcn_cvt_pk_fp8_f32(v[i].z * inv, v[i].w * inv, w0, true);
        *(int*)(xo + ((i << 6) + lane) * 4) = w0;
    }
}

// ---- scan helper (R12: packed-f16, 2 cols/instruction; additive chunk rotate) ----
__device__ __forceinline__ void scan_half_row(const _Float16* Dt_,
        const unsigned short* labcam_cols,
        int srow, int shalf, int pli, float (&pos5)[5], float (&neg5)[5]) {
    const int jb = shalf * 64;
    const int s2 = 2 * (srow & 7);
    const int pli2 = pli * 0x00010001;
    const int ONE2  = 0x3C003C00;   // half2(1.0, 1.0)
    const int BOOST2= 0x398E398E;   // half2(1/1.44) = 0.694336
    const int PINF2 = 0x7C007C00;
    const int NINF2 = 0xFC00FC00;
    half2v p5[5], n5[5];
#pragma unroll
    for (int k = 0; k < 5; ++k) { p5[k] = bits2h(NINF2); n5[k] = bits2h(PINF2); }
#pragma unroll
    for (int c8 = 0; c8 < 8; ++c8) {
        const int pc = ((shalf * 8 + c8) + s2) & 15;      // physical 16B chunk
        intx4 v  = *(const intx4*)(Dt_ + srow * DT_LD + pc * 8);
        intx4 lc = *(const intx4*)(labcam_cols + jb + c8 * 8);
#pragma unroll
        for (int e = 0; e < 4; ++e) {
            const int d2p = v[e];                 // 2 packed f16 d2 values
            const int x   = pli2 ^ lc[e];         // 2 packed (label<<4|cam) xors
            const int mdl = nzmask16(x & 0xFFF0FFF0);       // FFFF = diff label
            const int mdc = nzmask16_small(x & 0x000F000F); // FFFF = diff cam
            // negative: diff label; same-cam boost d2 * (1/1.44) (monotone in dist/1.2)
            const int mul = bfi(mdc, ONE2, BOOST2);
            half2v nv = bits2h(d2p) * bits2h(mul);          // v_pk_mul_f16
            nv = bits2h(bfi(mdl, h2bits(nv), PINF2));       // same-label -> +inf
            ins_asc2(n5, nv);                               // unconditional: P(any-lane insert)~1
            // positive: same label AND diff cam (i==j auto-excluded: same cam)
            const int pmask = mdc & ~mdl;
            half2v pv = bits2h(bfi(pmask, d2p, NINF2));
            half2v chk = __builtin_elementwise_max(pv, p5[4]);
            if (h2bits(chk) != h2bits(p5[4])) ins_desc2(p5, pv);  // ~40% taken
        }
    }
    // fold hi-halves into lo halves: rotate 16 and insert (top5 ⊆ union of half-top5s)
    half2v tp[5], tn[5];
#pragma unroll
    for (int k = 0; k < 5; ++k) {
        tp[k] = bits2h((int)__builtin_amdgcn_alignbit((unsigned)h2bits(p5[k]), (unsigned)h2bits(p5[k]), 16));
        tn[k] = bits2h((int)__builtin_amdgcn_alignbit((unsigned)h2bits(n5[k]), (unsigned)h2bits(n5[k]), 16));
    }
#pragma unroll
    for (int k = 0; k < 5; ++k) { ins_desc2(p5, tp[k]); ins_asc2(n5, tn[k]); }
#pragma unroll
    for (int k = 0; k < 5; ++k) { pos5[k] = (float)p5[k][0]; neg5[k] = (float)n5[k][0]; }
}

// merge the two half-row lists (adjacent lanes; snapshot-then-insert) and emit.
// R13: [slot][row] layout, 16B slots (5 vals + 3 sentinels) -> ONE coalesced b128
// store per list (was 10 scattered b16 stores: 91MB WRITE + ~90MB RMW FETCH).
__device__ __forceinline__ void emit_lists(float (&pos5)[5], float (&neg5)[5], int shalf,
        _Float16* posp, _Float16* negp, int gi, int slot) {
    float tp[5], tn[5];
#pragma unroll
    for (int k = 0; k < 5; ++k) { tp[k] = __shfl_xor(pos5[k], 1); tn[k] = __shfl_xor(neg5[k], 1); }
#pragma unroll
    for (int k = 0; k < 5; ++k) {
        if (tp[k] > pos5[4]) ins_desc(pos5, tp[k]);
        if (tn[k] < neg5[4]) ins_asc(neg5, tn[k]);
    }
    if (shalf == 0) {
        const float NINF = -__builtin_inff(), PINF = __builtin_inff();
        halfx8 hp, hn;
#pragma unroll
        for (int k = 0; k < 5; ++k) { hp[k] = (_Float16)pos5[k]; hn[k] = (_Float16)neg5[k]; }
        hp[5] = hp[6] = hp[7] = (_Float16)NINF;
        hn[5] = hn[6] = hn[7] = (_Float16)PINF;
        const size_t off = ((size_t)slot * NROW + gi) * SLOT_P;
        *(halfx8*)(posp + off) = hp;
        *(halfx8*)(negp + off) = hn;
    }
}

// ---- kernel 2 (sym): R13 = R12 + double-buffered 2-phase K-loop.
// Old: bar -> issue loads -> bar(vmcnt0 drain right after issue) = full L2-miss
// latency exposed per stage x16 (latency-bound: no pipe >42% in R12 counters).
// New: issue stage t+1 into buf^1 BEFORE computing stage t; ONE barrier/stage;
// the vmcnt(0) drain lands after ~770cy of ds_read+MFMA -> latency hidden.
// LDS: 64KB staging (2 bufs) + Dt aliases it + 2KB side = 67.6KB -> 2 blocks/CU
// (accepted: latency-bound, not LDS/MFMA-throughput-bound).
__global__ __launch_bounds__(256, 2) void k_gemm_sym(
        const unsigned char* __restrict__ xb, const float* __restrict__ sq,
        const int* __restrict__ labels, const int* __restrict__ camids,
        _Float16* __restrict__ posp, _Float16* __restrict__ negp) {
    __shared__ __align__(16) char smem[65536 + 2048];
    // staging buf b: As_b = smem + b*32768 (16KB), Bs_b = As_b + 16384 (16KB)
    _Float16* Dt = (_Float16*)smem;           // [0, 34816) aliases staging
    float* sqr_s = (float*)(smem + 65536);
    float* sqc_s = sqr_s + BM;
    unsigned short* labcam_a = (unsigned short*)(sqc_s + BM);
    unsigned short* labcam_b = labcam_a + BM;

    const int tid = threadIdx.x;
    const int w = tid >> 6, lane = tid & 63;
    const int wm = w >> 1, wn = w & 1;

    // tile decode: off-diagonal pairs (b<a) first, diagonals last (cheap tail)
    int a, b;
    {
        int bx = blockIdx.x;
        if (bx < NOFF) {
            a = (int)((1.0f + sqrtf(8.0f * (float)bx + 1.0f)) * 0.5f);
            while (a * (a - 1) / 2 > bx) --a;
            while (a * (a + 1) / 2 <= bx) ++a;
            b = bx - a * (a - 1) / 2;
        } else {
            a = b = bx - NOFF;
        }
    }
    const int r0 = a * BM, c0 = b * BM;

    const int lr = lane >> 3;                  // staging: row within 8-row chunk
    const int lc = ((lane & 7) ^ lr) * 16;     // staging: swizzled source chunk, bytes

    auto stage = [&](int buf, int kkv) {
        char* Asb = smem + (buf << 15);
        char* Bsb = Asb + 16384;
#pragma unroll
        for (int q = 0; q < 4; ++q) {
            const int ra = w * 32 + q * 8;     // wave-uniform 8-row chunk base
            load_lds16(xb + (size_t)(r0 + ra + lr) * NDIM + kkv + lc, Asb + ra * BKB);
            load_lds16(xb + (size_t)(c0 + ra + lr) * NDIM + kkv + lc, Bsb + ra * BKB);
        }
    };

    stage(0, 0);                     // prefetch first K-tile before anything else

    if (tid < BM) {
        int gi = r0 + tid;
        sqr_s[tid] = sq[gi];
        labcam_a[tid] = (unsigned short)((labels[gi] << 4) | camids[gi]);
    } else {
        int t2 = tid - BM;
        int gj = c0 + t2;
        sqc_s[t2] = sq[gj];
        labcam_b[t2] = (unsigned short)((labels[gj] << 4) | camids[gj]);
    }

    const int srow = tid >> 1;       // scan: 2 threads per row
    const int shalf = tid & 1;

    const int m16 = lane & 15;
    const int quad = lane >> 4;
    const int s7 = m16 & 7;                    // frag-read swizzle key (= row&7)
    const int pc0 = ((2 * quad) ^ s7) * 16;    // physical byte offset of logical chunk 2q
    const int pc1 = ((2 * quad + 1) ^ s7) * 16;

    floatx4 acc[4][4];
#pragma unroll
    for (int mi = 0; mi < 4; ++mi)
#pragma unroll
        for (int ni = 0; ni < 4; ++ni) {
            floatx4 z = {0.f, 0.f, 0.f, 0.f};
            acc[mi][ni] = z;
        }

    __syncthreads();                 // stage0 landed (vmcnt0) + side arrays visible

    for (int t = 0; t < 16; ++t) {   // 2-phase: prefetch t+1 || compute t
        const int cur = t & 1;
        if (t < 15) stage(cur ^ 1, (t + 1) * BKB);
        const char* Ab = smem + (cur << 15);
        const char* Bb = Ab + 16384;
        intx8 bfr[4];
#pragma unroll
        for (int ni = 0; ni < 4; ++ni) {
            const char* bp = Bb + (wn * 64 + ni * 16 + m16) * BKB;
            intx4 lo = *(const intx4*)(bp + pc0);
            intx4 hi = *(const intx4*)(bp + pc1);
            bfr[ni] = __builtin_shufflevector(lo, hi, 0, 1, 2, 3, 4, 5, 6, 7);
        }
        __builtin_amdgcn_s_setprio(1);
#pragma unroll
        for (int mi = 0; mi < 4; ++mi) {
            const char* ap = Ab + (wm * 64 + mi * 16 + m16) * BKB;
            intx4 lo = *(const intx4*)(ap + pc0);
            intx4 hi = *(const intx4*)(ap + pc1);
            intx8 af = __builtin_shufflevector(lo, hi, 0, 1, 2, 3, 4, 5, 6, 7);
#pragma unroll
            for (int ni = 0; ni < 4; ++ni)
                acc[mi][ni] = __builtin_amdgcn_mfma_scale_f32_16x16x128_f8f6f4(
                    af, bfr[ni], acc[mi][ni], 0, 0, 0, 127, 0, 127);
        }
        __builtin_amdgcn_s_setprio(0);
        __syncthreads();             // retires buf reads; drains prefetch (issued ~770cy ago)
    }
    // last iter's syncthreads retired all staging reads -> Dt overwrite safe

    // ---- pass 1: d2 row-major (additive chunk rotate); scan rows of strip a ----
    // 16x16 C layout: col = lane&15, row = quad*4 + reg
#pragma unroll
    for (int mi = 0; mi < 4; ++mi) {
        const int il = wm * 64 + mi * 16 + quad * 4;
#pragma unroll
        for (int ni = 0; ni < 4; ++ni) {
            const int jl = wn * 64 + ni * 16 + m16;
            const float sj = sqc_s[jl];
#pragma unroll
            for (int r = 0; r < 4; ++r) {
                float d2 = fmaxf(sqr_s[il + r] + sj - 2.0f * acc[mi][ni][r], 1e-12f);
                const int pch = (((jl >> 3) + 2 * ((il + r) & 7)) & 15);
                Dt[(il + r) * DT_LD + (pch << 3) + (jl & 7)] = (_Float16)d2;
            }
        }
    }
    __syncthreads();

    float pos5[5], neg5[5];
    scan_half_row(Dt, labcam_b, srow, shalf, (int)labcam_a[srow], pos5, neg5);
    emit_lists(pos5, neg5, shalf, posp, negp, r0 + srow, b);

    if (a != b) {
        __syncthreads();             // pass-1 scan reads done before Dt overwrite
        // ---- pass 2: d2 transposed (b64 packed, additive rotate); scan rows of strip b ----
#pragma unroll
        for (int ni = 0; ni < 4; ++ni) {
            const int jl = wn * 64 + ni * 16 + m16;
            const float sj = sqc_s[jl];
            const int cw2 = 2 * (jl & 7);
#pragma unroll
            for (int mi = 0; mi < 4; ++mi) {
                const int il = wm * 64 + mi * 16 + quad * 4;
                halfx4 h;
#pragma unroll
                for (int r = 0; r < 4; ++r)
                    h[r] = (_Float16)fmaxf(sqr_s[il + r] + sj - 2.0f * acc[mi][ni][r], 1e-12f);
                const int pch = (((il >> 3) + cw2) & 15);
                *(halfx4*)(Dt + jl * DT_LD + (pch << 3) + (il & 7)) = h;
            }
        }
        __syncthreads();
        scan_half_row(Dt, labcam_a, srow, shalf, (int)labcam_b[srow], pos5, neg5);
        emit_lists(pos5, neg5, shalf, posp, negp, c0 + srow, a);
    }
}

// ---- kernel 3: merge 64 fp16 d2-lists/row.  R13: [slot][row] layout -> every
// wave-load is 64 consecutive rows x 16B = 1KB coalesced.  256 blocks x 256 thr
// (32 rows/block, 8 slot-groups of 8); cross-group merge via swizzled LDS stash.
__global__ __launch_bounds__(256) void k_merge_sym(const _Float16* __restrict__ posp,
        const _Float16* __restrict__ negp, const int* __restrict__ epoch_p,
        float* __restrict__ out, float* __restrict__ wsum_p, float* __restrict__ wpsum_p) {
    const int t = threadIdx.x;
    const int rl = t & 31;                      // row within block
    const int sg = t >> 5;                      // slot group 0..7 (8 slots each)
    const int row = blockIdx.x * 32 + rl;
    const float NINF = -__builtin_inff(), PINF = __builtin_inff();
    float p5[5] = {NINF, NINF, NINF, NINF, NINF};
    float n5[5] = {PINF, PINF, PINF, PINF, PINF};
    const size_t rbase = (size_t)row * SLOT_P;
#pragma unroll
    for (int s = 0; s < 8; ++s) {
        const size_t off = (size_t)(sg * 8 + s) * ((size_t)NROW * SLOT_P) + rbase;
        halfx8 pv = *(const halfx8*)(posp + off);
        halfx8 nv = *(const halfx8*)(negp + off);
#pragma unroll
        for (int e = 0; e < 8; ++e) { float f = (float)pv[e]; if (f > p5[4]) ins_desc(p5, f); }
#pragma unroll
        for (int e = 0; e < 8; ++e) { float f = (float)nv[e]; if (f < n5[4]) ins_asc(n5, f); }
    }
    __shared__ __align__(16) _Float16 lp[32][8][8];
    __shared__ __align__(16) _Float16 ln[32][8][8];
    const int sw = (sg + rl) & 7;               // bank-spread the 16B stash slots
    {
        halfx8 hp, hn;
#pragma unroll
        for (int k = 0; k < 5; ++k) { hp[k] = (_Float16)p5[k]; hn[k] = (_Float16)n5[k]; }
        hp[5] = hp[6] = hp[7] = (_Float16)NINF;
        hn[5] = hn[6] = hn[7] = (_Float16)PINF;
        *(halfx8*)&lp[rl][sw][0] = hp;
        *(halfx8*)&ln[rl][sw][0] = hn;
    }
    __syncthreads();
    if (t < 32) {
        float P5[5] = {NINF, NINF, NINF, NINF, NINF};
        float N5[5] = {PINF, PINF, PINF, PINF, PINF};
#pragma unroll
        for (int g = 0; g < 8; ++g) {
            halfx8 pv = *(const halfx8*)&lp[t][g][0];
            halfx8 nv = *(const halfx8*)&ln[t][g][0];
#pragma unroll
            for (int e = 0; e < 8; ++e) { float f = (float)pv[e]; if (f > P5[4]) ins_desc(P5, f); }
#pragma unroll
            for (int e = 0; e < 8; ++e) { float f = (float)nv[e]; if (f < N5[4]) ins_asc(N5, f); }
        }
        // d2 -> dist on the 5 survivors only
        float s = 0.f; int c = 0;
#pragma unroll
        for (int k = 0; k < 5; ++k) { bool fin = (P5[k] > NINF); s += fin ? sqrtf(P5[k]) : 0.f; c += fin ? 1 : 0; }
        float d_ap = (c > 0) ? s / (float)c : NINF;
        s = 0.f; c = 0;
#pragma unroll
        for (int k = 0; k < 5; ++k) { bool fin = (N5[k] < PINF); s += fin ? sqrtf(N5[k]) : 0.f; c += fin ? 1 : 0; }
        float d_an = (c > 0) ? s / (float)c : PINF;

        const int orow = blockIdx.x * 32 + t;
        out[1 + orow] = d_ap;
        out[1 + NROW + orow] = d_an;
        float diff = d_ap - d_an;
        float w0 = 1.0f / (1.0f + expf(-2.0f * diff));       // sigmoid(ALPHA*(d_ap-d_an))
        float p;
        if (*epoch_p < 10) {
            p = fmaxf(diff, 0.0f) + log1pf(expf(-fabsf(diff)));  // stable softplus
        } else {
            p = fmaxf(diff + 0.3f, 0.0f);                    // relu(d_ap - d_an + MARGIN)
        }
        float wp = w0 * p;
#pragma unroll
        for (int o = 16; o > 0; o >>= 1) { w0 += __shfl_down(w0, o, 32); wp += __shfl_down(wp, o, 32); }
        if (t == 0) { wsum_p[blockIdx.x] = w0; wpsum_p[blockIdx.x] = wp; }
    }
}

// ---- kernel 4: finalize loss scalar (256 partials, one wave) ----
__global__ void k_finalize(const float* __restrict__ wsum_p, const float* __restrict__ wpsum_p,
                           float* __restrict__ out) {
    const int t = threadIdx.x;   // 64 threads
    float sw  = wsum_p[t] + wsum_p[t + 64] + wsum_p[t + 128] + wsum_p[t + 192];
    float swp = wpsum_p[t] + wpsum_p[t + 64] + wpsum_p[t + 128] + wpsum_p[t + 192];
#pragma unroll
    for (int o = 32; o > 0; o >>= 1) { sw += __shfl_down(sw, o); swp += __shfl_down(swp, o); }
    if (t == 0) {
        float M = fmaxf(sw / (float)NROW, 1e-12f);
        out[0] = swp / ((float)NROW * M);
    }
}

extern "C" void kernel_launch(void* const* d_in, const int* in_sizes, int n_in,
                              void* d_out, int out_size, void* d_ws, size_t ws_size,
                              hipStream_t stream) {
    const float* feats  = (const float*)d_in[0];
    const int*   labels = (const int*)d_in[1];
    const int*   camids = (const int*)d_in[2];
    const int*   epoch  = (const int*)d_in[3];
    float* out = (float*)d_out;
    char* ws = (char*)d_ws;

    // workspace layout (~33.6 MB; ws proven >= 44 MB in R4-R11)
    unsigned char* xb = (unsigned char*)ws;                            // 16,777,216 B
    float* sq = (float*)(ws + 16777216);                               //     32,768 B
    const size_t LIST_HALVES = (size_t)KL_SYM * NROW * SLOT_P;         // 4,194,304 halves = 8 MB
    _Float16* posp = (_Float16*)(ws + 16777216 + 32768);
    _Float16* negp = posp + LIST_HALVES;
    float* wsum_p  = (float*)((char*)(posp + 2 * LIST_HALVES));
    float* wpsum_p = wsum_p + MERGE_BLOCKS;

    k_normalize<<<NROW / 4, 256, 0, stream>>>(feats, xb, sq);
    k_gemm_sym<<<NTILE, 256, 0, stream>>>(xb, sq, labels, camids, posp, negp);
    k_merge_sym<<<MERGE_BLOCKS, 256, 0, stream>>>(posp, negp, epoch, out, wsum_p, wpsum_p);
    k_finalize<<<1, 64, 0, stream>>>(wsum_p, wpsum_p, out);
}